// Round 5
// baseline (75.157 us; speedup 1.0000x reference)
//
#include <hip/hip_runtime.h>
#include <math.h>

#define NN 256
#define NF 24
#define RCUT 6.0f
#define PI_F 3.14159265358979323846f
#define NSEG 16        // segments per (b,i); 4 waves/block -> grid.z = NSEG/4

// d_ws layout (bytes):
//   [0, 2048)                     m_arr:  int[B*NN]
//   [4096, 4096+2M)               geoC:   float4[B*NN][NN]  dx,dy,dz,rinv
//   [4096+2M, 4096+4M)            wgtC:   float4[B*NN][NN]  fc, e(-.01r2), e(-.1r2), 0
//   [4096+4M, +512K)              part:   float[B*NN][NSEG][16]
#define GEO_OFF  (4096)
#define WGT_OFF  (4096 + 2*1024*1024)
#define PART_OFF (4096 + 4*1024*1024)

// ---------------- setup: one wave per (b,i) ----------------
__global__ __launch_bounds__(64) void setup_kernel(
    const float* __restrict__ Z,
    const float* __restrict__ coords,   // [B,N,3]
    float* __restrict__ out,            // [B,N,24] (writes features 0..7)
    void* __restrict__ wsv)
{
    const int i = blockIdx.x, b = blockIdx.y, lane = threadIdx.x;
    const int ai = b * NN + i;
    int* m_arr = (int*)wsv;
    float4* geoC = (float4*)((char*)wsv + GEO_OFF) + (size_t)ai * NN;
    float4* wgtC = (float4*)((char*)wsv + WGT_OFF) + (size_t)ai * NN;

    const float* cb = coords + (size_t)b * NN * 3;
    const float xi = cb[i * 3 + 0], yi = cb[i * 3 + 1], zi = cb[i * 3 + 2];

    float acc[7];
#pragma unroll
    for (int t = 0; t < 7; t++) acc[t] = 0.0f;

    int m = 0;
#pragma unroll
    for (int rnd = 0; rnd < 4; ++rnd) {
        const int j = lane + (rnd << 6);
        const float xj = cb[j * 3 + 0], yj = cb[j * 3 + 1], zj = cb[j * 3 + 2];
        const float dx = xi - xj, dy = yi - yj, dz = zi - zj;
        const float r2 = dx * dx + dy * dy + dz * dz;
        const float r  = sqrtf(r2);
        const bool incut = (j != i) && (r < RCUT);
        const float fc = incut ? 0.5f * (__cosf((PI_F / RCUT) * r) + 1.0f) : 0.0f;
        acc[0] += fc;
        acc[1] += __expf(-0.1f * r2) * fc;
        acc[2] += __expf(-1.0f * r2) * fc;
        const float d = r - 2.0f;
        acc[3] += __expf(-0.1f * d * d) * fc;
        acc[4] += __expf(-1.0f * d * d) * fc;
        acc[5] += __cosf(r) * fc;
        acc[6] += __cosf(2.0f * r) * fc;
        const unsigned long long bal = __ballot(incut);
        if (incut) {
            const int p = m + __popcll(bal & ((1ULL << lane) - 1ULL));
            geoC[p] = make_float4(dx, dy, dz, 1.0f / r);
            wgtC[p] = make_float4(fc, __expf(-0.01f * r2), __expf(-0.1f * r2), 0.0f);
        }
        m += __popcll(bal);
    }
    if (lane == 0) m_arr[ai] = m;

#pragma unroll
    for (int t = 0; t < 7; t++) {
        float v = acc[t];
        for (int off = 32; off > 0; off >>= 1) v += __shfl_down(v, off, 64);
        acc[t] = v;
    }
    if (lane == 0) {
        float* ob = out + (size_t)ai * NF;
        ob[0] = Z[i];
#pragma unroll
        for (int t = 0; t < 7; t++) ob[1 + t] = acc[t];
    }
}

// ---------------- pair: 4 waves per block, wave = one segment ----------------
__global__ __launch_bounds__(256) void pair_kernel(
    const void* __restrict__ wsv_in, void* __restrict__ wsv_out)
{
    const int i = blockIdx.x, b = blockIdx.y;
    const int tid = threadIdx.x, lane = tid & 63, wave = tid >> 6;
    const int seg = blockIdx.z * 4 + wave;
    const int ai = b * NN + i;

    const int* m_arr = (const int*)wsv_in;
    const float4* geoC = (const float4*)((const char*)wsv_in + GEO_OFF) + (size_t)ai * NN;
    const float4* wgtC = (const float4*)((const char*)wsv_in + WGT_OFF) + (size_t)ai * NN;
    float* part = (float*)((char*)wsv_out + PART_OFF);

    __shared__ float4 geo[NN];
    __shared__ float4 wgt[NN];
    __shared__ float red[4][16];

    const int m = m_arr[ai];
    // cooperative global->LDS load of compacted lists (4 waves share it)
    for (int idx = tid; idx < m; idx += 256) {
        geo[idx] = geoC[idx];
        wgt[idx] = wgtC[idx];
    }
    __syncthreads();

    float acc[16];
#pragma unroll
    for (int t = 0; t < 16; t++) acc[t] = 0.0f;

    if (m >= 2) {
        // round-robin unordered pairing: slot jj pairs with (jj+t)%m,
        // t=1..(m-1)/2 covers each pair once; even m adds half-round t=m/2
        // for jj<m/2 (assigned to last seg). x2 folded into reduce scale.
        const int Rfull = (m - 1) >> 1;
        const int tlo = 1 + (Rfull * seg) / NSEG;
        const int thi = (Rfull * (seg + 1)) / NSEG;
        const bool halfseg = (seg == NSEG - 1) && ((m & 1) == 0);
        const int mh = m >> 1;
        for (int rnd = 0; rnd < 4; ++rnd) {
            const int jj = lane + (rnd << 6);
            if (jj >= m) break;
            const float4 gj = geo[jj];
            const float4 wj = wgt[jj];
            for (int t = tlo; t <= thi + (halfseg && jj < mh ? 1 : 0); ++t) {
                int kk = jj + ((t > thi) ? mh : t); if (kk >= m) kk -= m;
                const float4 g = geo[kk];
                const float4 w = wgt[kk];
                const float ddx = gj.x - g.x, ddy = gj.y - g.y, ddz = gj.z - g.z;
                const float sqjk = ddx * ddx + ddy * ddy + ddz * ddz;
                const float rjk = sqrtf(sqjk);
                const float fcjk = (rjk < RCUT) ? 0.5f * (__cosf((PI_F / RCUT) * rjk) + 1.0f) : 0.0f;
                const float dot = gj.x * g.x + gj.y * g.y + gj.z * g.z;
                const float cost = dot * gj.w * g.w;
                const float base = wj.x * w.x;
                const float f3 = base * fcjk;
                const float e2a = wj.y * w.y;
                const float e2b = wj.z * w.z;
                const float e3a = e2a * __expf(-0.01f * sqjk);
                const float e3b = e2b * __expf(-0.1f * sqjk);
                const float c1m = fmaxf(1.0f - cost, 0.0f);
                const float c1p = fmaxf(1.0f + cost, 0.0f);
                const float c2m = c1m * c1m, c2p = c1p * c1p;
                const float c4m = c2m * c2m, c4p = c2p * c2p;
                const float w3a = e3a * f3, w3b = e3b * f3;
                const float w2a = e2a * base, w2b = e2b * base;
                acc[0]  += c1m * w3a;  acc[1]  += c1p * w3a;
                acc[2]  += c4m * w3a;  acc[3]  += c4p * w3a;
                acc[4]  += c1m * w3b;  acc[5]  += c1p * w3b;
                acc[6]  += c4m * w3b;  acc[7]  += c4p * w3b;
                acc[8]  += c1m * w2a;  acc[9]  += c1p * w2a;
                acc[10] += c4m * w2a;  acc[11] += c4p * w2a;
                acc[12] += c1m * w2b;  acc[13] += c1p * w2b;
                acc[14] += c4m * w2b;  acc[15] += c4p * w2b;
            }
        }
    }

#pragma unroll
    for (int t = 0; t < 16; t++) {
        float v = acc[t];
        for (int off = 32; off > 0; off >>= 1) v += __shfl_down(v, off, 64);
        if (lane == 0) red[wave][t] = v;
    }
    __syncthreads();
    if (tid < 64) {
        const int w2 = tid >> 4, f = tid & 15;
        part[((size_t)ai * NSEG + (blockIdx.z * 4 + w2)) * 16 + f] = red[w2][f];
    }
}

// ---------------- reduce: angular features 8..23 ----------------
__global__ __launch_bounds__(256) void reduce_kernel(
    const void* __restrict__ wsv, float* __restrict__ out)
{
    const int idx = blockIdx.x * 256 + threadIdx.x;   // over B*NN*16 = 8192
    const int f  = idx & 15;
    const int ai = idx >> 4;
    const float* p = (const float*)((const char*)wsv + PART_OFF)
                   + ((size_t)ai * NSEG) * 16 + f;
    float v = 0.0f;
#pragma unroll
    for (int s = 0; s < NSEG; ++s) v += p[s * 16];
    // unordered-pair x2; per group of 4: (z1,-),(z1,+),(z4,-),(z4,+); 2^(1-4)=0.125
    v *= ((f & 3) >= 2) ? 0.25f : 2.0f;
    out[(size_t)ai * NF + 8 + f] = v;
}

extern "C" void kernel_launch(void* const* d_in, const int* in_sizes, int n_in,
                              void* d_out, int out_size, void* d_ws, size_t ws_size,
                              hipStream_t stream) {
    const float* Z = (const float*)d_in[0];       // [256]
    const float* coords = (const float*)d_in[1];  // [2,256,3]
    float* out = (float*)d_out;                   // [2,256,24]
    setup_kernel<<<dim3(NN, 2), dim3(64), 0, stream>>>(Z, coords, out, d_ws);
    pair_kernel<<<dim3(NN, 2, NSEG / 4), dim3(256), 0, stream>>>(d_ws, d_ws);
    reduce_kernel<<<dim3(2 * NN * 16 / 256), dim3(256), 0, stream>>>(d_ws, out);
}

// Round 6
// 67.960 us; speedup vs baseline: 1.1059x; 1.1059x over previous
//
#include <hip/hip_runtime.h>
#include <math.h>

#define NN 256
#define NF 24
#define RCUT 6.0f
#define PI_F 3.14159265358979323846f
#define NSEG 8   // 8 waves per block, wave = segment of the t-range

// Single-dispatch fused featurizer: one block per (b,i), 512 threads (8 waves).
// Setup (waves 0-3) -> ballot-compacted neighbor list in LDS -> all 8 waves
// split the round-robin unordered-pair t-range -> block reduce -> direct store.
__global__ __launch_bounds__(512, 4) void feat_kernel(
    const float* __restrict__ Z,       // [N]
    const float* __restrict__ coords,  // [B,N,3]
    float* __restrict__ out)           // [B,N,24]
{
    const int i = blockIdx.x, b = blockIdx.y;
    const int tid = threadIdx.x, lane = tid & 63, wave = tid >> 6;

    __shared__ float4 geo[NN];     // compacted: dx,dy,dz,rinv  (dvec = c_i - c_j)
    __shared__ float4 wgt[NN];     // compacted: fc, e(-.01r2), e(-.1r2), 0
    __shared__ int   wave_cnt[4];
    __shared__ float rad[4][7];    // radial partials (setup waves)
    __shared__ float red[8][16];   // angular partials (all waves)

    const float* cb = coords + (size_t)b * NN * 3;
    const float xi = cb[i * 3 + 0], yi = cb[i * 3 + 1], zi = cb[i * 3 + 2];

    // ---- setup: waves 0..3, j = tid (0..255) ----
    float dx = 0, dy = 0, dz = 0, r2 = 0, r = 0, fc = 0;
    bool incut = false;
    if (tid < NN) {
        const float xj = cb[tid * 3 + 0], yj = cb[tid * 3 + 1], zj = cb[tid * 3 + 2];
        dx = xi - xj; dy = yi - yj; dz = zi - zj;
        r2 = dx * dx + dy * dy + dz * dz;
        r  = sqrtf(r2);
        incut = (tid != i) && (r < RCUT);
        fc = incut ? 0.5f * (__cosf((PI_F / RCUT) * r) + 1.0f) : 0.0f;

        float racc[7];
        racc[0] = fc;
        racc[1] = __expf(-0.1f * r2) * fc;
        racc[2] = __expf(-1.0f * r2) * fc;
        const float d = r - 2.0f;
        racc[3] = __expf(-0.1f * d * d) * fc;
        racc[4] = __expf(-1.0f * d * d) * fc;
        racc[5] = __cosf(r) * fc;
        racc[6] = __cosf(2.0f * r) * fc;
#pragma unroll
        for (int t = 0; t < 7; t++) {
            float v = racc[t];
            for (int off = 32; off > 0; off >>= 1) v += __shfl_down(v, off, 64);
            if (lane == 0) rad[wave][t] = v;
        }
        const unsigned long long bal = __ballot(incut);
        if (lane == 0) wave_cnt[wave] = __popcll(bal);
    }
    __syncthreads();

    const int m = wave_cnt[0] + wave_cnt[1] + wave_cnt[2] + wave_cnt[3];
    if (tid < NN && incut) {
        const unsigned long long bal = __ballot(incut);
        int base = 0;
#pragma unroll
        for (int w = 0; w < 4; w++) if (w < wave) base += wave_cnt[w];
        const int p = base + __popcll(bal & ((1ULL << lane) - 1ULL));
        geo[p] = make_float4(dx, dy, dz, 1.0f / r);
        wgt[p] = make_float4(fc, __expf(-0.01f * r2), __expf(-0.1f * r2), 0.0f);
    }
    __syncthreads();

    // ---- pair phase: all 8 waves; wave = t-range segment ----
    float acc[16];
#pragma unroll
    for (int t = 0; t < 16; t++) acc[t] = 0.0f;

    if (m >= 2) {
        // round-robin unordered pairing: slot jj with (jj+t)%m, t=1..(m-1)/2
        // covers each pair once; even m adds half-round t=m/2 for jj<m/2
        // (assigned to wave 7). x2 folded into the epilogue scale.
        const int Rfull = (m - 1) >> 1;
        const int tlo = 1 + (Rfull * wave) / NSEG;
        const int thi = (Rfull * (wave + 1)) / NSEG;
        const bool halfseg = (wave == NSEG - 1) && ((m & 1) == 0);
        const int mh = m >> 1;
        for (int rnd = 0; rnd < 4; ++rnd) {
            const int jj = lane + (rnd << 6);
            if (jj >= m) break;
            const float4 gj = geo[jj];
            const float4 wj = wgt[jj];
            const int tend = thi + ((halfseg && jj < mh) ? 1 : 0);
            for (int t = tlo; t <= tend; ++t) {
                int kk = jj + ((t > thi) ? mh : t); if (kk >= m) kk -= m;
                const float4 g = geo[kk];
                const float4 w = wgt[kk];
                const float ddx = gj.x - g.x, ddy = gj.y - g.y, ddz = gj.z - g.z;
                const float sqjk = ddx * ddx + ddy * ddy + ddz * ddz;
                const float rjk = sqrtf(sqjk);
                const float fcjk = (rjk < RCUT) ? 0.5f * (__cosf((PI_F / RCUT) * rjk) + 1.0f) : 0.0f;
                const float dot = gj.x * g.x + gj.y * g.y + gj.z * g.z;
                const float cost = dot * gj.w * g.w;
                const float base2 = wj.x * w.x;               // fcr_ij * fcr_ik
                const float f3 = base2 * fcjk;
                const float e2a = wj.y * w.y;                 // exp(-.01*(sqij+sqik))
                const float e2b = wj.z * w.z;                 // exp(-.1 *(sqij+sqik))
                const float e3a = e2a * __expf(-0.01f * sqjk);
                const float e3b = e2b * __expf(-0.1f * sqjk);
                const float c1m = fmaxf(1.0f - cost, 0.0f);
                const float c1p = fmaxf(1.0f + cost, 0.0f);
                const float c2m = c1m * c1m, c2p = c1p * c1p;
                const float c4m = c2m * c2m, c4p = c2p * c2p;
                const float w3a = e3a * f3, w3b = e3b * f3;
                const float w2a = e2a * base2, w2b = e2b * base2;
                acc[0]  += c1m * w3a;  acc[1]  += c1p * w3a;
                acc[2]  += c4m * w3a;  acc[3]  += c4p * w3a;
                acc[4]  += c1m * w3b;  acc[5]  += c1p * w3b;
                acc[6]  += c4m * w3b;  acc[7]  += c4p * w3b;
                acc[8]  += c1m * w2a;  acc[9]  += c1p * w2a;
                acc[10] += c4m * w2a;  acc[11] += c4p * w2a;
                acc[12] += c1m * w2b;  acc[13] += c1p * w2b;
                acc[14] += c4m * w2b;  acc[15] += c4p * w2b;
            }
        }
    }

#pragma unroll
    for (int t = 0; t < 16; t++) {
        float v = acc[t];
        for (int off = 32; off > 0; off >>= 1) v += __shfl_down(v, off, 64);
        if (lane == 0) red[wave][t] = v;
    }
    __syncthreads();

    // ---- epilogue (wave 0 only): direct store of all 24 features ----
    float* ob = out + ((size_t)b * NN + i) * NF;
    if (tid < 16) {
        float v = 0.0f;
#pragma unroll
        for (int w = 0; w < 8; w++) v += red[w][tid];
        // unordered-pair x2; per group of 4: (z1,-),(z1,+),(z4,-),(z4,+); 2^(1-4)=0.125
        v *= ((tid & 3) >= 2) ? 0.25f : 2.0f;
        ob[8 + tid] = v;
    } else if (tid >= 32 && tid < 39) {
        const int t = tid - 32;
        ob[1 + t] = rad[0][t] + rad[1][t] + rad[2][t] + rad[3][t];
    } else if (tid == 39) {
        ob[0] = Z[i];
    }
}

extern "C" void kernel_launch(void* const* d_in, const int* in_sizes, int n_in,
                              void* d_out, int out_size, void* d_ws, size_t ws_size,
                              hipStream_t stream) {
    const float* Z = (const float*)d_in[0];       // [256]
    const float* coords = (const float*)d_in[1];  // [2,256,3]
    float* out = (float*)d_out;                   // [2,256,24]
    feat_kernel<<<dim3(NN, 2), dim3(512), 0, stream>>>(Z, coords, out);
}

// Round 7
// 65.865 us; speedup vs baseline: 1.1411x; 1.0318x over previous
//
#include <hip/hip_runtime.h>
#include <math.h>

#define NN 256
#define NF 24
#define RCUT 6.0f
#define PI_F 3.14159265358979323846f
#define NSEG 8   // 8 waves per block, wave = segment of the t-range

// Single-dispatch fused featurizer: one block per (b,i), 512 threads (8 waves).
// Pair-body weights folded per-atom: A = fc*exp(-.01 r2), B = fc*exp(-.1 r2),
// so the inner loop reads float4 geo + float2 ab per k (was 2x float4).
__global__ __launch_bounds__(512, 4) void feat_kernel(
    const float* __restrict__ Z,       // [N]
    const float* __restrict__ coords,  // [B,N,3]
    float* __restrict__ out)           // [B,N,24]
{
    const int i = blockIdx.x, b = blockIdx.y;
    const int tid = threadIdx.x, lane = tid & 63, wave = tid >> 6;

    __shared__ float4 geo[NN];      // compacted: dx,dy,dz,rinv  (dvec = c_i - c_j)
    __shared__ float2 ab[NN];       // compacted: A = fc*e(-.01r2), B = fc*e(-.1r2)
    __shared__ int   wave_cnt[4];
    __shared__ float rad[4][7];     // radial partials (setup waves)
    __shared__ float red2[8][8][16];// angular partials: [wave][octet][feat]

    const float* cb = coords + (size_t)b * NN * 3;
    const float xi = cb[i * 3 + 0], yi = cb[i * 3 + 1], zi = cb[i * 3 + 2];

    // ---- setup: waves 0..3, j = tid (0..255) ----
    float dx = 0, dy = 0, dz = 0, r2 = 0, r = 0, fc = 0;
    bool incut = false;
    if (tid < NN) {
        const float xj = cb[tid * 3 + 0], yj = cb[tid * 3 + 1], zj = cb[tid * 3 + 2];
        dx = xi - xj; dy = yi - yj; dz = zi - zj;
        r2 = dx * dx + dy * dy + dz * dz;
        r  = sqrtf(r2);
        incut = (tid != i) && (r < RCUT);
        fc = incut ? 0.5f * (__cosf((PI_F / RCUT) * r) + 1.0f) : 0.0f;

        float racc[7];
        racc[0] = fc;
        racc[1] = __expf(-0.1f * r2) * fc;
        racc[2] = __expf(-1.0f * r2) * fc;
        const float d = r - 2.0f;
        racc[3] = __expf(-0.1f * d * d) * fc;
        racc[4] = __expf(-1.0f * d * d) * fc;
        racc[5] = __cosf(r) * fc;
        racc[6] = __cosf(2.0f * r) * fc;
#pragma unroll
        for (int t = 0; t < 7; t++) {
            float v = racc[t];
            for (int off = 32; off > 0; off >>= 1) v += __shfl_down(v, off, 64);
            if (lane == 0) rad[wave][t] = v;
        }
        const unsigned long long bal = __ballot(incut);
        if (lane == 0) wave_cnt[wave] = __popcll(bal);
    }
    __syncthreads();

    const int m = wave_cnt[0] + wave_cnt[1] + wave_cnt[2] + wave_cnt[3];
    if (tid < NN && incut) {
        const unsigned long long bal = __ballot(incut);
        int base = 0;
#pragma unroll
        for (int w = 0; w < 4; w++) if (w < wave) base += wave_cnt[w];
        const int p = base + __popcll(bal & ((1ULL << lane) - 1ULL));
        geo[p] = make_float4(dx, dy, dz, 1.0f / r);
        ab[p]  = make_float2(fc * __expf(-0.01f * r2), fc * __expf(-0.1f * r2));
    }
    __syncthreads();

    // ---- pair phase: all 8 waves; wave = t-range segment ----
    float acc[16];
#pragma unroll
    for (int t = 0; t < 16; t++) acc[t] = 0.0f;

    if (m >= 2) {
        // round-robin unordered pairing: slot jj with (jj+t)%m, t=1..(m-1)/2
        // covers each pair once; even m adds half-round t=m/2 for jj<m/2
        // (assigned to wave 7). x2 folded into the epilogue scale.
        const int Rfull = (m - 1) >> 1;
        const int tlo = 1 + (Rfull * wave) / NSEG;
        const int thi = (Rfull * (wave + 1)) / NSEG;
        const bool halfseg = (wave == NSEG - 1) && ((m & 1) == 0);
        const int mh = m >> 1;
        for (int rnd = 0; rnd < 4; ++rnd) {
            const int jj = lane + (rnd << 6);
            if (jj >= m) break;
            const float4 gj = geo[jj];
            const float2 aj = ab[jj];
            const int tend = thi + ((halfseg && jj < mh) ? 1 : 0);
#pragma unroll 2
            for (int t = tlo; t <= tend; ++t) {
                int kk = jj + ((t > thi) ? mh : t); if (kk >= m) kk -= m;
                const float4 g = geo[kk];
                const float2 a = ab[kk];
                const float ddx = gj.x - g.x, ddy = gj.y - g.y, ddz = gj.z - g.z;
                const float sqjk = ddx * ddx + ddy * ddy + ddz * ddz;
                const float rjk = sqrtf(sqjk);
                const float fcjk = (rjk < RCUT) ? 0.5f * (__cosf((PI_F / RCUT) * rjk) + 1.0f) : 0.0f;
                const float dot = gj.x * g.x + gj.y * g.y + gj.z * g.z;
                const float cost = dot * gj.w * g.w;
                const float w2a = aj.x * a.x;            // fcj*fck*exp(-.01(sqij+sqik))
                const float w2b = aj.y * a.y;            // fcj*fck*exp(-.1 (sqij+sqik))
                const float t3a = fcjk * __expf(-0.01f * sqjk);
                const float t3b = fcjk * __expf(-0.1f * sqjk);
                const float w3a = w2a * t3a, w3b = w2b * t3b;
                const float c1m = 1.0f - cost;           // cost in [-1,1]: no clamp
                const float c1p = 1.0f + cost;
                const float c2m = c1m * c1m, c2p = c1p * c1p;
                const float c4m = c2m * c2m, c4p = c2p * c2p;
                acc[0]  += c1m * w3a;  acc[1]  += c1p * w3a;
                acc[2]  += c4m * w3a;  acc[3]  += c4p * w3a;
                acc[4]  += c1m * w3b;  acc[5]  += c1p * w3b;
                acc[6]  += c4m * w3b;  acc[7]  += c4p * w3b;
                acc[8]  += c1m * w2a;  acc[9]  += c1p * w2a;
                acc[10] += c4m * w2a;  acc[11] += c4p * w2a;
                acc[12] += c1m * w2b;  acc[13] += c1p * w2b;
                acc[14] += c4m * w2b;  acc[15] += c4p * w2b;
            }
        }
    }

    // ---- reduction: 3 shuffle levels -> lanes 0..7 hold octet partials,
    //      scatter to LDS, 128-thread gather ----
#pragma unroll
    for (int t = 0; t < 16; t++) {
        float v = acc[t];
        v += __shfl_down(v, 32, 64);
        v += __shfl_down(v, 16, 64);
        v += __shfl_down(v, 8, 64);
        acc[t] = v;
    }
    if (lane < 8) {
#pragma unroll
        for (int t = 0; t < 16; t++) red2[wave][lane][t] = acc[t];
    }
    __syncthreads();

    float* ob = out + ((size_t)b * NN + i) * NF;
    if (tid < 128) {
        const int f = tid >> 3, s = tid & 7;   // feature, octet-slot
        float v = 0.0f;
#pragma unroll
        for (int w = 0; w < 8; w++) v += red2[w][s][f];
        v += __shfl_down(v, 4, 8);
        v += __shfl_down(v, 2, 8);
        v += __shfl_down(v, 1, 8);
        if (s == 0) {
            // unordered-pair x2; per group of 4: (z1,-),(z1,+),(z4,-),(z4,+); 2^(1-4)=0.125
            v *= ((f & 3) >= 2) ? 0.25f : 2.0f;
            ob[8 + f] = v;
        }
    } else if (tid >= 128 && tid < 135) {
        const int t = tid - 128;
        ob[1 + t] = rad[0][t] + rad[1][t] + rad[2][t] + rad[3][t];
    } else if (tid == 135) {
        ob[0] = Z[i];
    }
}

extern "C" void kernel_launch(void* const* d_in, const int* in_sizes, int n_in,
                              void* d_out, int out_size, void* d_ws, size_t ws_size,
                              hipStream_t stream) {
    const float* Z = (const float*)d_in[0];       // [256]
    const float* coords = (const float*)d_in[1];  // [2,256,3]
    float* out = (float*)d_out;                   // [2,256,24]
    feat_kernel<<<dim3(NN, 2), dim3(512), 0, stream>>>(Z, coords, out);
}

// Round 8
// 65.523 us; speedup vs baseline: 1.1470x; 1.0052x over previous
//
#include <hip/hip_runtime.h>
#include <math.h>

#define NN 256
#define NF 24
#define RCUT 6.0f
#define PI_F 3.14159265358979323846f
#define NSEG 8   // 8 waves per block, wave = t-range segment

// TRIPLE=1: G45 triple features (fc3, needs rjk/fcjk/exp) -> out[8..15]
// TRIPLE=0: G45 pair features (fc2, NO transcendentals)   -> out[16..23]
template <bool TRIPLE>
__device__ __forceinline__ void pair_loop(
    const float4* __restrict__ geo, const float2* __restrict__ ab,
    int m, int wave, int lane, float* acc)
{
    const int Rfull = (m - 1) >> 1;
    const int tlo = 1 + ((Rfull * wave) >> 3);
    const int thi = (Rfull * (wave + 1)) >> 3;
    const int mh = m >> 1;
    for (int rnd = 0; rnd < 4; ++rnd) {
        const int jj = lane + (rnd << 6);
        if (jj >= m) break;
        const float4 gj = geo[jj];
        const float2 aj = ab[jj];
        for (int t = tlo; t <= thi; ++t) {
            const int kk = jj + t;               // unwrapped: geo/ab extended by Rfull
            const float4 g = geo[kk];
            const float2 a = ab[kk];
            const float dot = gj.x * g.x + gj.y * g.y + gj.z * g.z;
            const float cost = dot * gj.w * g.w;
            float wa = aj.x * a.x;               // fcj*fck*exp(-.01(sqij+sqik))
            float wb = aj.y * a.y;               // fcj*fck*exp(-.1 (sqij+sqik))
            if (TRIPLE) {
                const float ddx = gj.x - g.x, ddy = gj.y - g.y, ddz = gj.z - g.z;
                const float sqjk = ddx * ddx + ddy * ddy + ddz * ddz;
                const float rjk = sqrtf(sqjk);
                const float fcjk = (rjk < RCUT) ? 0.5f * (__cosf((PI_F / RCUT) * rjk) + 1.0f) : 0.0f;
                wa *= fcjk * __expf(-0.01f * sqjk);
                wb *= fcjk * __expf(-0.1f * sqjk);
            }
            const float c1m = 1.0f - cost, c1p = 1.0f + cost;
            const float c2m = c1m * c1m, c2p = c1p * c1p;
            const float c4m = c2m * c2m, c4p = c2p * c2p;
            acc[0] += c1m * wa;  acc[1] += c1p * wa;
            acc[2] += c4m * wa;  acc[3] += c4p * wa;
            acc[4] += c1m * wb;  acc[5] += c1p * wb;
            acc[6] += c4m * wb;  acc[7] += c4p * wb;
        }
        // half-round for even m (wave 7 only): pair (jj, jj+m/2), jj < m/2
        if (wave == NSEG - 1 && (m & 1) == 0 && jj < mh) {
            const int kk = jj + mh;
            const float4 g = geo[kk];
            const float2 a = ab[kk];
            const float dot = gj.x * g.x + gj.y * g.y + gj.z * g.z;
            const float cost = dot * gj.w * g.w;
            float wa = aj.x * a.x;
            float wb = aj.y * a.y;
            if (TRIPLE) {
                const float ddx = gj.x - g.x, ddy = gj.y - g.y, ddz = gj.z - g.z;
                const float sqjk = ddx * ddx + ddy * ddy + ddz * ddz;
                const float rjk = sqrtf(sqjk);
                const float fcjk = (rjk < RCUT) ? 0.5f * (__cosf((PI_F / RCUT) * rjk) + 1.0f) : 0.0f;
                wa *= fcjk * __expf(-0.01f * sqjk);
                wb *= fcjk * __expf(-0.1f * sqjk);
            }
            const float c1m = 1.0f - cost, c1p = 1.0f + cost;
            const float c2m = c1m * c1m, c2p = c1p * c1p;
            const float c4m = c2m * c2m, c4p = c2p * c2p;
            acc[0] += c1m * wa;  acc[1] += c1p * wa;
            acc[2] += c4m * wa;  acc[3] += c4p * wa;
            acc[4] += c1m * wb;  acc[5] += c1p * wb;
            acc[6] += c4m * wb;  acc[7] += c4p * wb;
        }
    }
}

// grid (NN, B, 2): z=0 triple feats + radial + Z; z=1 pair feats. Disjoint
// outputs -> no atomics, one dispatch, 1024 blocks = HW-max residency.
__global__ __launch_bounds__(512, 4) void feat_kernel(
    const float* __restrict__ Z,       // [N]
    const float* __restrict__ coords,  // [B,N,3]
    float* __restrict__ out)           // [B,N,24]
{
    const int i = blockIdx.x, b = blockIdx.y, half = blockIdx.z;
    const int tid = threadIdx.x, lane = tid & 63, wave = tid >> 6;

    __shared__ float4 geo[NN + 128];  // +Rfull extension for unwrapped kk
    __shared__ float2 ab[NN + 128];
    __shared__ int   wave_cnt[4];
    __shared__ float rad[4][7];
    __shared__ float red2[8][8][8];   // [wave][octet][feat]

    const float* cb = coords + (size_t)b * NN * 3;
    const float xi = cb[i * 3 + 0], yi = cb[i * 3 + 1], zi = cb[i * 3 + 2];

    // ---- setup: waves 0..3, j = tid ----
    float dx = 0, dy = 0, dz = 0, r2 = 0, r = 0, fc = 0;
    bool incut = false;
    if (tid < NN) {
        const float xj = cb[tid * 3 + 0], yj = cb[tid * 3 + 1], zj = cb[tid * 3 + 2];
        dx = xi - xj; dy = yi - yj; dz = zi - zj;
        r2 = dx * dx + dy * dy + dz * dz;
        r  = sqrtf(r2);
        incut = (tid != i) && (r < RCUT);
        fc = incut ? 0.5f * (__cosf((PI_F / RCUT) * r) + 1.0f) : 0.0f;
        if (half == 0) {            // radial features only in the z=0 block
            float racc[7];
            racc[0] = fc;
            racc[1] = __expf(-0.1f * r2) * fc;
            racc[2] = __expf(-1.0f * r2) * fc;
            const float d = r - 2.0f;
            racc[3] = __expf(-0.1f * d * d) * fc;
            racc[4] = __expf(-1.0f * d * d) * fc;
            racc[5] = __cosf(r) * fc;
            racc[6] = __cosf(2.0f * r) * fc;
#pragma unroll
            for (int t = 0; t < 7; t++) {
                float v = racc[t];
                for (int off = 32; off > 0; off >>= 1) v += __shfl_down(v, off, 64);
                if (lane == 0) rad[wave][t] = v;
            }
        }
        const unsigned long long bal = __ballot(incut);
        if (lane == 0) wave_cnt[wave] = __popcll(bal);
    }
    __syncthreads();

    const int m = wave_cnt[0] + wave_cnt[1] + wave_cnt[2] + wave_cnt[3];
    if (tid < NN && incut) {
        const unsigned long long bal = __ballot(incut);
        int base = 0;
#pragma unroll
        for (int w = 0; w < 4; w++) if (w < wave) base += wave_cnt[w];
        const int p = base + __popcll(bal & ((1ULL << lane) - 1ULL));
        geo[p] = make_float4(dx, dy, dz, 1.0f / r);
        ab[p]  = make_float2(fc * __expf(-0.01f * r2), fc * __expf(-0.1f * r2));
    }
    __syncthreads();
    // extension so kk = jj + t needs no wrap (kk <= m-1 + Rfull)
    const int Rext = (m >= 2) ? ((m - 1) >> 1) : 0;
    for (int s = tid; s < Rext; s += 512) { geo[m + s] = geo[s]; ab[m + s] = ab[s]; }
    __syncthreads();

    float acc[8];
#pragma unroll
    for (int t = 0; t < 8; t++) acc[t] = 0.0f;
    if (m >= 2) {
        if (half == 0) pair_loop<true>(geo, ab, m, wave, lane, acc);
        else           pair_loop<false>(geo, ab, m, wave, lane, acc);
    }

    // ---- reduction: 3 shuffle levels -> octet partials -> LDS -> 64-thread gather
#pragma unroll
    for (int t = 0; t < 8; t++) {
        float v = acc[t];
        v += __shfl_down(v, 32, 64);
        v += __shfl_down(v, 16, 64);
        v += __shfl_down(v, 8, 64);
        acc[t] = v;
    }
    if (lane < 8) {
#pragma unroll
        for (int t = 0; t < 8; t++) red2[wave][lane][t] = acc[t];
    }
    __syncthreads();

    float* ob = out + ((size_t)b * NN + i) * NF;
    if (tid < 64) {
        const int f = tid >> 3, s = tid & 7;
        float v = 0.0f;
#pragma unroll
        for (int w = 0; w < 8; w++) v += red2[w][s][f];
        v += __shfl_down(v, 4, 8);
        v += __shfl_down(v, 2, 8);
        v += __shfl_down(v, 1, 8);
        if (s == 0) {
            // unordered-pair x2; per group of 4: (z1,-),(z1,+),(z4,-),(z4,+); 2^(1-4)=0.125
            v *= ((f & 3) >= 2) ? 0.25f : 2.0f;
            ob[(half ? 16 : 8) + f] = v;
        }
    } else if (half == 0 && tid >= 64 && tid < 71) {
        const int t = tid - 64;
        ob[1 + t] = rad[0][t] + rad[1][t] + rad[2][t] + rad[3][t];
    } else if (half == 0 && tid == 71) {
        ob[0] = Z[i];
    }
}

extern "C" void kernel_launch(void* const* d_in, const int* in_sizes, int n_in,
                              void* d_out, int out_size, void* d_ws, size_t ws_size,
                              hipStream_t stream) {
    const float* Z = (const float*)d_in[0];       // [256]
    const float* coords = (const float*)d_in[1];  // [2,256,3]
    float* out = (float*)d_out;                   // [2,256,24]
    feat_kernel<<<dim3(NN, 2, 2), dim3(512), 0, stream>>>(Z, coords, out);
}

// Round 9
// 63.809 us; speedup vs baseline: 1.1778x; 1.0269x over previous
//
#include <hip/hip_runtime.h>
#include <math.h>

#define NN 256
#define NF 24
#define RCUT 6.0f
#define PI_F 3.14159265358979323846f
#define CS 0.27415568f   // (pi/6)^2 : u = CS * sq_jk

// fc(sq) = 0.5*(1+cos(pi*sqrt(sq)/6)) as even Taylor in u = CS*sq (exact
// series of cos with x^2=u; |err| <= 5.2e-5 on [0,36])
__device__ __forceinline__ float fc_poly(float u) {
    float p = 1.0438378e-9f;
    p = fmaf(p, u, -1.3778659e-7f);
    p = fmaf(p, u,  1.2400794e-5f);
    p = fmaf(p, u, -6.9444444e-4f);
    p = fmaf(p, u,  2.0833333e-2f);
    p = fmaf(p, u, -0.25f);
    p = fmaf(p, u,  1.0f);
    return p;
}

// One block per (b,i), 512 threads. Waves 0-5: O(m^2) triple features
// (t-range split 6 ways). Waves 6-7: O(m) moment accumulation for the pair
// features (one eta each): S_p = sum multinomial * M_alpha^2. Single dispatch.
__global__ __launch_bounds__(512, 4) void feat_kernel(
    const float* __restrict__ Z,       // [N]
    const float* __restrict__ coords,  // [B,N,3]
    float* __restrict__ out)           // [B,N,24]
{
    const int i = blockIdx.x, b = blockIdx.y;
    const int tid = threadIdx.x, lane = tid & 63, wave = tid >> 6;

    __shared__ float4 geo[NN + 128];   // compacted: ux,uy,uz,r (unit vec + dist)
    __shared__ float4 ab[NN + 128];    // compacted: A=fc*e(-.01r2), B=fc*e(-.1r2), r2, 0
    __shared__ int   wave_cnt[4];
    __shared__ float rad[4][7];
    __shared__ float red[6][8][8];     // triple partials [wave][octet][feat]
    __shared__ float mom[2][64][36];   // per-lane moment partials [eta][lane][comp]
    __shared__ float momsum[2][36];

    const float* cb = coords + (size_t)b * NN * 3;
    const float xi = cb[i * 3 + 0], yi = cb[i * 3 + 1], zi = cb[i * 3 + 2];

    // ---- setup: waves 0..3, j = tid ----
    float dx = 0, dy = 0, dz = 0, r2 = 0, r = 0, fc = 0;
    bool incut = false;
    if (tid < NN) {
        const float xj = cb[tid * 3 + 0], yj = cb[tid * 3 + 1], zj = cb[tid * 3 + 2];
        dx = xi - xj; dy = yi - yj; dz = zi - zj;
        r2 = dx * dx + dy * dy + dz * dz;
        r  = sqrtf(r2);
        incut = (tid != i) && (r < RCUT);
        fc = incut ? 0.5f * (__cosf((PI_F / RCUT) * r) + 1.0f) : 0.0f;
        float racc[7];
        racc[0] = fc;
        racc[1] = __expf(-0.1f * r2) * fc;
        racc[2] = __expf(-1.0f * r2) * fc;
        const float d = r - 2.0f;
        racc[3] = __expf(-0.1f * d * d) * fc;
        racc[4] = __expf(-1.0f * d * d) * fc;
        racc[5] = __cosf(r) * fc;
        racc[6] = __cosf(2.0f * r) * fc;
#pragma unroll
        for (int t = 0; t < 7; t++) {
            float v = racc[t];
            for (int off = 32; off > 0; off >>= 1) v += __shfl_down(v, off, 64);
            if (lane == 0) rad[wave][t] = v;
        }
        const unsigned long long bal = __ballot(incut);
        if (lane == 0) wave_cnt[wave] = __popcll(bal);
    }
    __syncthreads();

    const int m = wave_cnt[0] + wave_cnt[1] + wave_cnt[2] + wave_cnt[3];
    if (tid < NN && incut) {
        const unsigned long long bal = __ballot(incut);
        int base = 0;
#pragma unroll
        for (int w = 0; w < 4; w++) if (w < wave) base += wave_cnt[w];
        const int p = base + __popcll(bal & ((1ULL << lane) - 1ULL));
        const float rinv = 1.0f / r;
        geo[p] = make_float4(dx * rinv, dy * rinv, dz * rinv, r);
        ab[p]  = make_float4(fc * __expf(-0.01f * r2), fc * __expf(-0.1f * r2), r2, 0.0f);
    }
    __syncthreads();
    const int Rext = (m >= 2) ? ((m - 1) >> 1) : 0;   // unwrap extension
    for (int s = tid; s < Rext; s += 512) { geo[m + s] = geo[s]; ab[m + s] = ab[s]; }
    __syncthreads();

    if (wave < 6) {
        // ---- triple features: round-robin unordered pairs, t-split 6 ways ----
        float acc[8];
#pragma unroll
        for (int t = 0; t < 8; t++) acc[t] = 0.0f;
        if (m >= 2) {
            const int Rfull = (m - 1) >> 1;
            const int tlo = 1 + (Rfull * wave) / 6;
            const int thi = (Rfull * (wave + 1)) / 6;
            const int mh = m >> 1;
            const bool doHalf = (wave == 5) && ((m & 1) == 0);
            for (int rnd = 0; rnd < 4; ++rnd) {
                const int jj = lane + (rnd << 6);
                if (jj >= m) break;
                const float4 gj = geo[jj];
                const float4 aj = ab[jj];
                const float r2j = aj.z;
                const float gw2 = -2.0f * gj.w;
                const int tend = thi + ((doHalf && jj < mh) ? 1 : 0);
                for (int t = tlo; t <= tend; ++t) {
                    const int kk = jj + ((t > thi) ? mh : t);
                    const float4 g = geo[kk];
                    const float4 a = ab[kk];
                    const float cost = fmaf(gj.x, g.x, fmaf(gj.y, g.y, gj.z * g.z));
                    const float s = fmaf(gw2 * g.w, cost, r2j + a.z);   // sq_jk
                    const float pfc = fc_poly(CS * s);
                    const float fcjk = (s < 36.0f) ? pfc : 0.0f;
                    const float ea = __expf(-0.01f * s);
                    const float eb = __expf(-0.1f * s);
                    const float wa = (aj.x * a.x) * (fcjk * ea);
                    const float wb = (aj.y * a.y) * (fcjk * eb);
                    const float c1m = 1.0f - cost, c1p = 1.0f + cost;
                    const float c2m = c1m * c1m, c2p = c1p * c1p;
                    const float c4m = c2m * c2m, c4p = c2p * c2p;
                    acc[0] += c1m * wa;  acc[1] += c1p * wa;
                    acc[2] += c4m * wa;  acc[3] += c4p * wa;
                    acc[4] += c1m * wb;  acc[5] += c1p * wb;
                    acc[6] += c4m * wb;  acc[7] += c4p * wb;
                }
            }
        }
#pragma unroll
        for (int t = 0; t < 8; t++) {
            float v = acc[t];
            v += __shfl_down(v, 32, 64);
            v += __shfl_down(v, 16, 64);
            v += __shfl_down(v, 8, 64);
            acc[t] = v;
        }
        if (lane < 8) {
#pragma unroll
            for (int t = 0; t < 8; t++) red[wave][lane][t] = acc[t];
        }
    } else {
        // ---- pair features via moments: eta e = wave-6, w = A or B ----
        const int e = wave - 6;
        float mm[36];
#pragma unroll
        for (int q = 0; q < 36; q++) mm[q] = 0.0f;
        for (int rnd = 0; rnd < 4; ++rnd) {
            const int jj = lane + (rnd << 6);
            if (jj >= m) break;
            const float4 g = geo[jj];
            const float4 a = ab[jj];
            const float w = (e == 0) ? a.x : a.y;
            const float x = g.x, y = g.y, z = g.z;
            mm[0] += w;
            const float wx = w * x, wy = w * y, wz = w * z;
            mm[1] += wx; mm[2] += wy; mm[3] += wz;
            const float wxx = wx * x, wxy = wx * y, wxz = wx * z;
            const float wyy = wy * y, wyz = wy * z, wzz = wz * z;
            mm[4] += wxx; mm[5] += wxy; mm[6] += wxz;
            mm[7] += wyy; mm[8] += wyz; mm[9] += wzz;
            const float wxxx = wxx * x, wxxy = wxx * y, wxxz = wxx * z;
            const float wxyy = wxy * y, wxyz = wxy * z, wxzz = wxz * z;
            const float wyyy = wyy * y, wyyz = wyy * z, wyzz = wyz * z, wzzz = wzz * z;
            mm[10] += wxxx; mm[11] += wxxy; mm[12] += wxxz; mm[13] += wxyy;
            mm[14] += wxyz; mm[15] += wxzz; mm[16] += wyyy; mm[17] += wyyz;
            mm[18] += wyzz; mm[19] += wzzz;
            mm[20] += wxxx * x; mm[21] += wxxx * y; mm[22] += wxxx * z;
            mm[23] += wxxy * y; mm[24] += wxxy * z; mm[25] += wxxz * z;
            mm[26] += wxyy * y; mm[27] += wxyy * z; mm[28] += wxyz * z;
            mm[29] += wxzz * z; mm[30] += wyyy * y; mm[31] += wyyy * z;
            mm[32] += wyyz * z; mm[33] += wyzz * z; mm[34] += wzzz * z;
            mm[35] = fmaf(w, w, mm[35]);                      // diagonal D
        }
#pragma unroll
        for (int q = 0; q < 36; q++) mom[e][lane][q] = mm[q];
        // intra-wave reduce (same wave wrote all 64 rows; lockstep => no barrier)
        if (lane < 36) {
            float v0 = 0, v1 = 0, v2 = 0, v3 = 0;
#pragma unroll
            for (int j = 0; j < 64; j += 4) {
                v0 += mom[e][j + 0][lane]; v1 += mom[e][j + 1][lane];
                v2 += mom[e][j + 2][lane]; v3 += mom[e][j + 3][lane];
            }
            momsum[e][lane] = (v0 + v1) + (v2 + v3);
        }
    }
    __syncthreads();

    // ---- epilogue ----
    float* ob = out + ((size_t)b * NN + i) * NF;
    if (tid < 64) {
        const int f = tid >> 3, s = tid & 7;
        float v = 0.0f;
#pragma unroll
        for (int w = 0; w < 6; w++) v += red[w][s][f];
        v += __shfl_down(v, 4, 8);
        v += __shfl_down(v, 2, 8);
        v += __shfl_down(v, 1, 8);
        if (s == 0) {
            v *= ((f & 3) >= 2) ? 0.25f : 2.0f;   // x2 unordered; 2^(1-4)=0.125 for z4
            ob[8 + f] = v;
        }
    } else if (tid < 72) {
        const int f = tid - 64, e = f >> 2, sub = f & 3;
        const float* M = momsum[e];
        const float S0 = M[0] * M[0];
        const float S1 = M[1] * M[1] + M[2] * M[2] + M[3] * M[3];
        const float S2 = M[4] * M[4] + M[7] * M[7] + M[9] * M[9]
                       + 2.f * (M[5] * M[5] + M[6] * M[6] + M[8] * M[8]);
        const float S3 = M[10] * M[10] + M[16] * M[16] + M[19] * M[19]
                       + 3.f * (M[11] * M[11] + M[12] * M[12] + M[13] * M[13]
                              + M[15] * M[15] + M[17] * M[17] + M[18] * M[18])
                       + 6.f * M[14] * M[14];
        const float S4 = M[20] * M[20] + M[30] * M[30] + M[34] * M[34]
                       + 4.f * (M[21] * M[21] + M[22] * M[22] + M[26] * M[26]
                              + M[29] * M[29] + M[31] * M[31] + M[33] * M[33])
                       + 6.f * (M[23] * M[23] + M[25] * M[25] + M[32] * M[32])
                       + 12.f * (M[24] * M[24] + M[27] * M[27] + M[28] * M[28]);
        const float D = M[35];
        const float lam = (sub & 1) ? 1.0f : -1.0f;
        float v;
        if (sub < 2) v = S0 + lam * S1 - (1.0f + lam) * D;
        else         v = 0.125f * (S0 + 6.f * S2 + S4 + lam * 4.f * (S1 + S3)
                                   - ((sub == 3) ? 16.f * D : 0.0f));
        ob[16 + f] = v;
    } else if (tid < 79) {
        const int t = tid - 72;
        ob[1 + t] = rad[0][t] + rad[1][t] + rad[2][t] + rad[3][t];
    } else if (tid == 79) {
        ob[0] = Z[i];
    }
}

extern "C" void kernel_launch(void* const* d_in, const int* in_sizes, int n_in,
                              void* d_out, int out_size, void* d_ws, size_t ws_size,
                              hipStream_t stream) {
    const float* Z = (const float*)d_in[0];       // [256]
    const float* coords = (const float*)d_in[1];  // [2,256,3]
    float* out = (float*)d_out;                   // [2,256,24]
    feat_kernel<<<dim3(NN, 2), dim3(512), 0, stream>>>(Z, coords, out);
}

// Round 10
// 63.087 us; speedup vs baseline: 1.1913x; 1.0114x over previous
//
#include <hip/hip_runtime.h>
#include <math.h>

#define NN 256
#define NF 24
#define RCUT 6.0f
#define PI_F 3.14159265358979323846f
#define CS 0.27415568f   // (pi/6)^2 : u = CS * sq_jk

// fc(sq) = 0.5*(1+cos(pi*sqrt(sq)/6)) as even Taylor in u = CS*sq; |err|<=5.2e-5
__device__ __forceinline__ float fc_poly(float u) {
    float p = 1.0438378e-9f;
    p = fmaf(p, u, -1.3778659e-7f);
    p = fmaf(p, u,  1.2400794e-5f);
    p = fmaf(p, u, -6.9444444e-4f);
    p = fmaf(p, u,  2.0833333e-2f);
    p = fmaf(p, u, -0.25f);
    p = fmaf(p, u,  1.0f);
    return p;
}

// grid (NN, B, 2): z = eta half. All 8 waves split the triple t-range; wave 0
// additionally does the O(m) moment pass for this eta's pair features.
__global__ __launch_bounds__(512, 4) void feat_kernel(
    const float* __restrict__ Z,       // [N]
    const float* __restrict__ coords,  // [B,N,3]
    float* __restrict__ out)           // [B,N,24]
{
    const int i = blockIdx.x, b = blockIdx.y, e = blockIdx.z;  // e: 0=eta.01, 1=eta.1
    const int tid = threadIdx.x, lane = tid & 63, wave = tid >> 6;
    const float ETA = e ? 0.1f : 0.01f;

    __shared__ float4 geo[NN + 128];   // compacted: ux,uy,uz,r
    __shared__ float2 ab[NN + 128];    // compacted: W=fc*exp(-eta*r2), r2
    __shared__ int   wave_cnt[4];
    __shared__ float rad[4][7];
    __shared__ float red[8][8][4];     // triple partials [wave][octet][feat]
    __shared__ float mom[64][36];      // moment partials (wave 0 only)
    __shared__ float momsum[36];

    const float* cb = coords + (size_t)b * NN * 3;
    const float xi = cb[i * 3 + 0], yi = cb[i * 3 + 1], zi = cb[i * 3 + 2];

    // ---- setup: waves 0..3, j = tid ----
    float dx = 0, dy = 0, dz = 0, r2 = 0, r = 0, fc = 0;
    bool incut = false;
    if (tid < NN) {
        const float xj = cb[tid * 3 + 0], yj = cb[tid * 3 + 1], zj = cb[tid * 3 + 2];
        dx = xi - xj; dy = yi - yj; dz = zi - zj;
        r2 = dx * dx + dy * dy + dz * dz;
        r  = sqrtf(r2);
        incut = (tid != i) && (r < RCUT);
        fc = incut ? 0.5f * (__cosf((PI_F / RCUT) * r) + 1.0f) : 0.0f;
        if (e == 0) {                  // radial features only in the z=0 block
            float racc[7];
            racc[0] = fc;
            racc[1] = __expf(-0.1f * r2) * fc;
            racc[2] = __expf(-1.0f * r2) * fc;
            const float d = r - 2.0f;
            racc[3] = __expf(-0.1f * d * d) * fc;
            racc[4] = __expf(-1.0f * d * d) * fc;
            racc[5] = __cosf(r) * fc;
            racc[6] = __cosf(2.0f * r) * fc;
#pragma unroll
            for (int t = 0; t < 7; t++) {
                float v = racc[t];
                for (int off = 32; off > 0; off >>= 1) v += __shfl_down(v, off, 64);
                if (lane == 0) rad[wave][t] = v;
            }
        }
        const unsigned long long bal = __ballot(incut);
        if (lane == 0) wave_cnt[wave] = __popcll(bal);
    }
    __syncthreads();

    const int m = wave_cnt[0] + wave_cnt[1] + wave_cnt[2] + wave_cnt[3];
    if (tid < NN && incut) {
        const unsigned long long bal = __ballot(incut);
        int base = 0;
#pragma unroll
        for (int w = 0; w < 4; w++) if (w < wave) base += wave_cnt[w];
        const int p = base + __popcll(bal & ((1ULL << lane) - 1ULL));
        const float rinv = 1.0f / r;
        geo[p] = make_float4(dx * rinv, dy * rinv, dz * rinv, r);
        ab[p]  = make_float2(fc * __expf(-ETA * r2), r2);
    }
    __syncthreads();
    const int Rext = (m >= 2) ? ((m - 1) >> 1) : 0;   // unwrap extension
    for (int s = tid; s < Rext; s += 512) { geo[m + s] = geo[s]; ab[m + s] = ab[s]; }
    __syncthreads();

    // ---- triple features (this eta): round-robin pairs, t-split 8 ways ----
    float acc[4] = {0.0f, 0.0f, 0.0f, 0.0f};
    if (m >= 2) {
        const int Rfull = (m - 1) >> 1;
        const int tlo = 1 + ((Rfull * wave) >> 3);
        const int thi = (Rfull * (wave + 1)) >> 3;
        const int mh = m >> 1;
        const bool doHalf = (wave == 7) && ((m & 1) == 0);
        for (int rnd = 0; rnd < 4; ++rnd) {
            const int jj = lane + (rnd << 6);
            if (jj >= m) break;
            const float4 gj = geo[jj];
            const float2 aj = ab[jj];
            const float r2j = aj.y;
            const float gw2 = -2.0f * gj.w;
            const int tend = thi + ((doHalf && jj < mh) ? 1 : 0);
            for (int t = tlo; t <= tend; ++t) {
                const int kk = jj + ((t > thi) ? mh : t);
                const float4 g = geo[kk];
                const float2 a = ab[kk];
                const float cost = fmaf(gj.x, g.x, fmaf(gj.y, g.y, gj.z * g.z));
                const float s = fmaf(gw2 * g.w, cost, r2j + a.y);   // sq_jk
                const float pfc = fc_poly(CS * s);
                const float fcjk = (s < 36.0f) ? pfc : 0.0f;
                const float w3 = (aj.x * a.x) * (fcjk * __expf(-ETA * s));
                const float c1m = 1.0f - cost, c1p = 1.0f + cost;
                const float c2m = c1m * c1m, c2p = c1p * c1p;
                acc[0] += c1m * w3;          acc[1] += c1p * w3;
                acc[2] += c2m * c2m * w3;    acc[3] += c2p * c2p * w3;
            }
        }
    }
#pragma unroll
    for (int t = 0; t < 4; t++) {
        float v = acc[t];
        v += __shfl_down(v, 32, 64);
        v += __shfl_down(v, 16, 64);
        v += __shfl_down(v, 8, 64);
        acc[t] = v;
    }
    if (lane < 8) {
#pragma unroll
        for (int t = 0; t < 4; t++) red[wave][lane][t] = acc[t];
    }

    // ---- O(m) moment pass for pair features (wave 0, after its triple share) ----
    if (wave == 0) {
        float mm[36];
#pragma unroll
        for (int q = 0; q < 36; q++) mm[q] = 0.0f;
        for (int rnd = 0; rnd < 4; ++rnd) {
            const int jj = lane + (rnd << 6);
            if (jj >= m) break;
            const float4 g = geo[jj];
            const float w = ab[jj].x;
            const float x = g.x, y = g.y, z = g.z;
            mm[0] += w;
            const float wx = w * x, wy = w * y, wz = w * z;
            mm[1] += wx; mm[2] += wy; mm[3] += wz;
            const float wxx = wx * x, wxy = wx * y, wxz = wx * z;
            const float wyy = wy * y, wyz = wy * z, wzz = wz * z;
            mm[4] += wxx; mm[5] += wxy; mm[6] += wxz;
            mm[7] += wyy; mm[8] += wyz; mm[9] += wzz;
            const float wxxx = wxx * x, wxxy = wxx * y, wxxz = wxx * z;
            const float wxyy = wxy * y, wxyz = wxy * z, wxzz = wxz * z;
            const float wyyy = wyy * y, wyyz = wyy * z, wyzz = wyz * z, wzzz = wzz * z;
            mm[10] += wxxx; mm[11] += wxxy; mm[12] += wxxz; mm[13] += wxyy;
            mm[14] += wxyz; mm[15] += wxzz; mm[16] += wyyy; mm[17] += wyyz;
            mm[18] += wyzz; mm[19] += wzzz;
            mm[20] += wxxx * x; mm[21] += wxxx * y; mm[22] += wxxx * z;
            mm[23] += wxxy * y; mm[24] += wxxy * z; mm[25] += wxxz * z;
            mm[26] += wxyy * y; mm[27] += wxyy * z; mm[28] += wxyz * z;
            mm[29] += wxzz * z; mm[30] += wyyy * y; mm[31] += wyyy * z;
            mm[32] += wyyz * z; mm[33] += wyzz * z; mm[34] += wzzz * z;
            mm[35] = fmaf(w, w, mm[35]);              // diagonal D
        }
#pragma unroll
        for (int q = 0; q < 36; q++) mom[lane][q] = mm[q];
        if (lane < 36) {                               // lockstep intra-wave reduce
            float v0 = 0, v1 = 0, v2 = 0, v3 = 0;
#pragma unroll
            for (int j = 0; j < 64; j += 4) {
                v0 += mom[j + 0][lane]; v1 += mom[j + 1][lane];
                v2 += mom[j + 2][lane]; v3 += mom[j + 3][lane];
            }
            momsum[lane] = (v0 + v1) + (v2 + v3);
        }
    }
    __syncthreads();

    // ---- epilogue ----
    float* ob = out + ((size_t)b * NN + i) * NF;
    if (tid < 32) {
        const int f = tid >> 3, s = tid & 7;
        float v = 0.0f;
#pragma unroll
        for (int w = 0; w < 8; w++) v += red[w][s][f];
        v += __shfl_down(v, 4, 8);
        v += __shfl_down(v, 2, 8);
        v += __shfl_down(v, 1, 8);
        if (s == 0) {
            v *= (f >= 2) ? 0.25f : 2.0f;   // x2 unordered; 2^(1-4)=0.125 for z4
            ob[8 + 4 * e + f] = v;
        }
    } else if (tid < 36) {
        const int sub = tid - 32;
        const float* M = momsum;
        const float S0 = M[0] * M[0];
        const float S1 = M[1] * M[1] + M[2] * M[2] + M[3] * M[3];
        const float S2 = M[4] * M[4] + M[7] * M[7] + M[9] * M[9]
                       + 2.f * (M[5] * M[5] + M[6] * M[6] + M[8] * M[8]);
        const float S3 = M[10] * M[10] + M[16] * M[16] + M[19] * M[19]
                       + 3.f * (M[11] * M[11] + M[12] * M[12] + M[13] * M[13]
                              + M[15] * M[15] + M[17] * M[17] + M[18] * M[18])
                       + 6.f * M[14] * M[14];
        const float S4 = M[20] * M[20] + M[30] * M[30] + M[34] * M[34]
                       + 4.f * (M[21] * M[21] + M[22] * M[22] + M[26] * M[26]
                              + M[29] * M[29] + M[31] * M[31] + M[33] * M[33])
                       + 6.f * (M[23] * M[23] + M[25] * M[25] + M[32] * M[32])
                       + 12.f * (M[24] * M[24] + M[27] * M[27] + M[28] * M[28]);
        const float D = M[35];
        const float lam = (sub & 1) ? 1.0f : -1.0f;
        float v;
        if (sub < 2) v = S0 + lam * S1 - (1.0f + lam) * D;
        else         v = 0.125f * (S0 + 6.f * S2 + S4 + lam * 4.f * (S1 + S3)
                                   - ((sub == 3) ? 16.f * D : 0.0f));
        ob[16 + 4 * e + sub] = v;
    } else if (e == 0 && tid >= 36 && tid < 43) {
        const int t = tid - 36;
        ob[1 + t] = rad[0][t] + rad[1][t] + rad[2][t] + rad[3][t];
    } else if (e == 0 && tid == 43) {
        ob[0] = Z[i];
    }
}

extern "C" void kernel_launch(void* const* d_in, const int* in_sizes, int n_in,
                              void* d_out, int out_size, void* d_ws, size_t ws_size,
                              hipStream_t stream) {
    const float* Z = (const float*)d_in[0];       // [256]
    const float* coords = (const float*)d_in[1];  // [2,256,3]
    float* out = (float*)d_out;                   // [2,256,24]
    feat_kernel<<<dim3(NN, 2, 2), dim3(512), 0, stream>>>(Z, coords, out);
}